// Round 1
// baseline (435.898 us; speedup 1.0000x reference)
//
#include <hip/hip_runtime.h>
#include <cstdint>
#include <cstddef>

typedef float f32x4 __attribute__((ext_vector_type(4)));
typedef short bf16x8 __attribute__((ext_vector_type(8)));

#define DEVI __device__ __forceinline__

namespace {

constexpr int BB = 8, LL = 1024, CC = 1536;
constexpr int HH = 8, KDIM = 64, VDIM = 192;
constexpr int NFEAT = 192, FSZ = 32;
constexpr float SCL = 0.125f;
constexpr int MR = BB * LL;     // 8192
constexpr int NQK = HH * KDIM;  // 512
constexpr int NVD = HH * VDIM;  // 1536

DEVI short f2bf(float f) {
  unsigned u = __float_as_uint(f);
  u = (u + 0x7FFFu + ((u >> 16) & 1u)) >> 16;
  return (short)u;
}

DEVI void gload_lds16(const void* g, void* l) {
  __builtin_amdgcn_global_load_lds(
      (const __attribute__((address_space(1))) void*)g,
      (__attribute__((address_space(3))) void*)l, 16, 0, 0);
}

// ---------------- convert f32 -> bf16 ----------------
__global__ void k_f32_to_bf16(const float* __restrict__ src, short* __restrict__ dst, int n) {
  int i0 = (blockIdx.x * blockDim.x + threadIdx.x) * 4;
  int stride = gridDim.x * blockDim.x * 4;
  for (int i = i0; i < n; i += stride) {
    float4 v = *reinterpret_cast<const float4*>(src + i);
    short4 o = { f2bf(v.x), f2bf(v.y), f2bf(v.z), f2bf(v.w) };
    *reinterpret_cast<short4*>(dst + i) = o;
  }
}

// ---------------- transpose f32 [R][Cd] -> bf16 [Cd][R] ----------------
__global__ void k_transpose_w(const float* __restrict__ src, short* __restrict__ dst, int R, int Cd) {
  __shared__ float tile[32][33];
  int c0 = blockIdx.x * 32, r0 = blockIdx.y * 32;
  int tx = threadIdx.x, ty = threadIdx.y;   // (32, 8)
  #pragma unroll
  for (int i = 0; i < 4; i++)
    tile[ty + i * 8][tx] = src[(size_t)(r0 + ty + i * 8) * Cd + c0 + tx];
  __syncthreads();
  #pragma unroll
  for (int i = 0; i < 4; i++)
    dst[(size_t)(c0 + ty + i * 8) * R + r0 + tx] = f2bf(tile[tx][ty + i * 8]);
}

// ---------------- V: [8192][1536] bf16 -> Vt [64][192][1024] bf16 ----------------
__global__ void k_transpose_v(const short* __restrict__ vb, short* __restrict__ vt) {
  __shared__ short tile[32][33];
  int bh = blockIdx.z;
  int b = bh >> 3, h = bh & 7;
  int v0 = blockIdx.y * 32;
  int s0 = blockIdx.x * 32;
  int tx = threadIdx.x, ty = threadIdx.y;
  #pragma unroll
  for (int i = 0; i < 4; i++)
    tile[ty + i * 8][tx] = vb[(size_t)(b * LL + s0 + ty + i * 8) * NVD + h * VDIM + v0 + tx];
  __syncthreads();
  #pragma unroll
  for (int i = 0; i < 4; i++)
    vt[(size_t)bh * VDIM * LL + (size_t)(v0 + ty + i * 8) * LL + s0 + tx] = tile[tx][ty + i * 8];
}

// ---------------- gamma pdf global max ----------------
__global__ void k_pdfmax(unsigned* slot) {
  int tid = blockIdx.x * blockDim.x + threadIdx.x;
  int nth = gridDim.x * blockDim.x;
  double lmax = 0.0;
  for (int idx = tid; idx < 2047 * FSZ; idx += nth) {
    int j = idx >> 5, i = idx & 31;
    double ap = (double)(j >= 1023 ? j - 1023 : 1023 - j);
    double mean = 32.0 + 32.0 * (double)i;
    double conc = (mean * (1.0 / 16.0)) * (mean * (1.0 / 16.0));
    double rate = mean * (1.0 / 256.0);
    double lp = (conc - 1.0) * log(ap) - rate * ap - lgamma(conc) + conc * log(rate);
    double pdf = exp(lp) + 1e-8;
    lmax = fmax(lmax, pdf);
  }
  float fv = (float)lmax;
  #pragma unroll
  for (int o = 32; o > 0; o >>= 1) fv = fmaxf(fv, __shfl_down(fv, o, 64));
  if ((threadIdx.x & 63) == 0) atomicMax(slot, __float_as_uint(fv));
}

// ---------------- build RB: row 0 = zeros, row j+1 = (basis[j] @ WR) ----------------
__global__ void k_build_r(const float* __restrict__ WR, const unsigned* __restrict__ slot,
                          short* __restrict__ rbuf) {
  __shared__ float feats[NFEAT];
  int jp = blockIdx.x;       // 0..2047
  int tid = threadIdx.x;     // 256
  if (jp == 0) {
    if (tid < KDIM) rbuf[tid] = 0;
    return;
  }
  int j = jp - 1;            // 0..2046
  int pos = j - (LL - 1);
  int api = pos < 0 ? -pos : pos;
  double ap = (double)api;
  float sgn = pos > 0 ? 1.0f : (pos < 0 ? -1.0f : 0.0f);
  if (tid < FSZ) {
    double xhl = 3.0 + 7.0 * (double)tid / 31.0;
    double hl = exp2(xhl);
    float fe = (float)exp2(-ap / hl);
    feats[tid] = fe; feats[FSZ + tid] = sgn * fe;
  } else if (tid < 2 * FSZ) {
    int i = tid - FSZ;
    double cw = exp2((double)(i + 1)) - 1.0;
    float fc = cw > ap ? 1.0f : 0.0f;
    feats[2 * FSZ + i] = fc; feats[3 * FSZ + i] = sgn * fc;
  } else if (tid < 3 * FSZ) {
    int i = tid - 2 * FSZ;
    double mean = 32.0 + 32.0 * (double)i;
    double conc = (mean * (1.0 / 16.0)) * (mean * (1.0 / 16.0));
    double rate = mean * (1.0 / 256.0);
    double lp = (conc - 1.0) * log(ap) - rate * ap - lgamma(conc) + conc * log(rate);
    double pdf = exp(lp) + 1e-8;
    float fg = (float)(pdf / (double)__uint_as_float(*slot));
    feats[4 * FSZ + i] = fg; feats[5 * FSZ + i] = sgn * fg;
  }
  __syncthreads();
  if (tid < KDIM) {
    float acc = 0.f;
    #pragma unroll 4
    for (int f = 0; f < NFEAT; f++) acc += feats[f] * WR[f * KDIM + tid];
    rbuf[jp * KDIM + tid] = f2bf(acc);
  }
}

// ---------------- bf16 MFMA GEMM: C = A[M,K] @ Bt[N,K]^T + bias ----------------
// MODE 0: bf16 store to D0.  MODE 1: D0=(val)*SCL bf16, D1=(val+bias2)*SCL bf16.  MODE 2: f32 store.
template<int MODE>
__global__ __launch_bounds__(256, 2)
void k_gemm(const short* __restrict__ A, const short* __restrict__ Bt,
            int Mdim, int Ndim, int Kdim,
            const float* __restrict__ bias, const float* __restrict__ bias2,
            void* __restrict__ D0, void* __restrict__ D1) {
  __shared__ short As[128][64];
  __shared__ short Bs[128][64];
  int m0 = blockIdx.x * 128, n0 = blockIdx.y * 128;
  int tid = threadIdx.x;
  int w = tid >> 6, l = tid & 63;
  int wr = (w >> 1) * 64, wc = (w & 1) * 64;

  f32x4 acc[4][4] = {};

  const short* ga = A + (size_t)(m0 + w * 8 + (l >> 3)) * Kdim + (l & 7) * 8;
  const short* gb = Bt + (size_t)(n0 + w * 8 + (l >> 3)) * Kdim + (l & 7) * 8;

  for (int k0 = 0; k0 < Kdim; k0 += 64) {
    #pragma unroll
    for (int i = 0; i < 4; i++) {
      gload_lds16(ga + (size_t)(i * 32) * Kdim + k0, &As[i * 32 + w * 8][0]);
      gload_lds16(gb + (size_t)(i * 32) * Kdim + k0, &Bs[i * 32 + w * 8][0]);
    }
    __syncthreads();
    #pragma unroll
    for (int kk = 0; kk < 2; kk++) {
      bf16x8 af[4], bfr[4];
      #pragma unroll
      for (int mi = 0; mi < 4; mi++)
        af[mi] = *(const bf16x8*)&As[wr + mi * 16 + (l & 15)][kk * 32 + (l >> 4) * 8];
      #pragma unroll
      for (int ni = 0; ni < 4; ni++)
        bfr[ni] = *(const bf16x8*)&Bs[wc + ni * 16 + (l & 15)][kk * 32 + (l >> 4) * 8];
      #pragma unroll
      for (int mi = 0; mi < 4; mi++)
        #pragma unroll
        for (int ni = 0; ni < 4; ni++)
          acc[mi][ni] = __builtin_amdgcn_mfma_f32_16x16x32_bf16(af[mi], bfr[ni], acc[mi][ni], 0, 0, 0);
    }
    __syncthreads();
  }

  int lr = (l >> 4) * 4, lc = l & 15;
  #pragma unroll
  for (int ni = 0; ni < 4; ni++) {
    int col = n0 + wc + ni * 16 + lc;
    float bvv = bias[col];
    float bv2 = (MODE == 1) ? bias2[col] : 0.f;
    #pragma unroll
    for (int mi = 0; mi < 4; mi++) {
      #pragma unroll
      for (int r = 0; r < 4; r++) {
        int row = m0 + wr + mi * 16 + lr + r;
        float val = acc[mi][ni][r] + bvv;
        if (MODE == 0) {
          ((short*)D0)[(size_t)row * Ndim + col] = f2bf(val);
        } else if (MODE == 1) {
          ((short*)D0)[(size_t)row * Ndim + col] = f2bf(val * SCL);
          ((short*)D1)[(size_t)row * Ndim + col] = f2bf((val + bv2) * SCL);
        } else {
          ((float*)D0)[(size_t)row * Ndim + col] = val;
        }
      }
    }
  }
}

// ---------------- flash attention with interleaved rel-shift term ----------------
// Qp = (Q+u)*SCL, Qs = Q*SCL (bf16, [8192][512]); Kb bf16 [8192][512];
// Vt bf16 [64][192][1024]; Rb bf16 [2048][64] (row 0 zeros); AO bf16 [8192][1536].
__global__ __launch_bounds__(256, 2)
void k_attn(const short* __restrict__ Qp, const short* __restrict__ Qs,
            const short* __restrict__ Kb, const short* __restrict__ Vt,
            const short* __restrict__ Rb, short* __restrict__ AO) {
  __shared__ short sQp[64][64];
  __shared__ short sQs[34][64];
  __shared__ short sK[64][64];
  __shared__ short sV[192][64];
  __shared__ float sS[64][64];
  __shared__ short sP[64][64];
  __shared__ float sM[64], sL[64], sF[64];

  int qt = blockIdx.x, bh = blockIdx.y;
  int b = bh >> 3, h = bh & 7;
  int q0 = qt * 64;
  int tid = threadIdx.x;
  int w = tid >> 6, l = tid & 63;
  int lr = (l >> 4) * 4, lc = l & 15;

  for (int idx = tid; idx < 64 * 8; idx += 256) {
    int r = idx >> 3, c = (idx & 7) * 8;
    *(uint4*)&sQp[r][c] = *(const uint4*)&Qp[(size_t)(b * LL + q0 + r) * NQK + h * KDIM + c];
  }
  int qs0 = q0 >> 1;
  for (int idx = tid; idx < 33 * 8; idx += 256) {
    int r = idx >> 3, c = (idx & 7) * 8;
    *(uint4*)&sQs[r][c] = *(const uint4*)&Qs[(size_t)(b * LL + qs0 + r) * NQK + h * KDIM + c];
  }
  if (tid < 64) { sM[tid] = -INFINITY; sL[tid] = 0.f; }

  f32x4 oacc[4][3] = {};

  for (int k0 = 0; k0 < LL; k0 += 64) {
    // stage K and V^T tiles
    for (int idx = tid; idx < 64 * 8; idx += 256) {
      int r = idx >> 3, c = (idx & 7) * 8;
      *(uint4*)&sK[r][c] = *(const uint4*)&Kb[(size_t)(b * LL + k0 + r) * NQK + h * KDIM + c];
    }
    for (int idx = tid; idx < 192 * 8; idx += 256) {
      int r = idx >> 3, c = (idx & 7) * 8;
      *(uint4*)&sV[r][c] = *(const uint4*)&Vt[(size_t)bh * VDIM * LL + (size_t)r * LL + k0 + c];
    }
    __syncthreads();

    // S1 = Qp . K^T  (wave w owns q rows [w*16, w*16+16))
    {
      f32x4 s1[4] = {};
      #pragma unroll
      for (int kk = 0; kk < 2; kk++) {
        bf16x8 aq = *(const bf16x8*)&sQp[w * 16 + lc][kk * 32 + (l >> 4) * 8];
        #pragma unroll
        for (int ni = 0; ni < 4; ni++) {
          bf16x8 bk = *(const bf16x8*)&sK[ni * 16 + lc][kk * 32 + (l >> 4) * 8];
          s1[ni] = __builtin_amdgcn_mfma_f32_16x16x32_bf16(aq, bk, s1[ni], 0, 0, 0);
        }
      }
      #pragma unroll
      for (int ni = 0; ni < 4; ni++)
        #pragma unroll
        for (int r = 0; r < 4; r++)
          sS[w * 16 + lr + r][ni * 16 + lc] = s1[ni][r];
    }
    __syncthreads();

    // S2 rel-shift term: waves 0,1 -> even q rows; waves 2,3 -> odd q rows
    {
      bool even = (w < 2);
      int rowbase = even ? w * 16 : ((w - 2) * 16 + 1);
      int ibase = even ? w * 16 : (w - 2) * 16;
      const short* rb = Rb + (size_t)(even ? (k0 + 1024) : k0) * KDIM;
      f32x4 s2[4] = {};
      #pragma unroll
      for (int kk = 0; kk < 2; kk++) {
        bf16x8 aq = *(const bf16x8*)&sQs[rowbase + lc][kk * 32 + (l >> 4) * 8];
        #pragma unroll
        for (int ni = 0; ni < 4; ni++) {
          bf16x8 br = *(const bf16x8*)&rb[(size_t)(ni * 16 + lc) * KDIM + kk * 32 + (l >> 4) * 8];
          s2[ni] = __builtin_amdgcn_mfma_f32_16x16x32_bf16(aq, br, s2[ni], 0, 0, 0);
        }
      }
      int off = even ? 0 : 1;
      #pragma unroll
      for (int ni = 0; ni < 4; ni++)
        #pragma unroll
        for (int r = 0; r < 4; r++) {
          int i = ibase + lr + r;
          sS[2 * i + off][ni * 16 + lc] += s2[ni][r];
        }
    }
    __syncthreads();

    // online softmax (4 threads per row)
    {
      int r = tid >> 2, sub = tid & 3;
      float sv[16];
      float mx = -INFINITY;
      #pragma unroll
      for (int jj = 0; jj < 16; jj++) {
        sv[jj] = sS[r][sub * 16 + jj];
        mx = fmaxf(mx, sv[jj]);
      }
      mx = fmaxf(mx, __shfl_xor(mx, 1, 64));
      mx = fmaxf(mx, __shfl_xor(mx, 2, 64));
      float mold = sM[r];
      float mnew = fmaxf(mold, mx);
      float fac = __expf(mold - mnew);
      float psum = 0.f;
      #pragma unroll
      for (int jj = 0; jj < 16; jj++) {
        float p = __expf(sv[jj] - mnew);
        psum += p;
        sP[r][sub * 16 + jj] = f2bf(p);
      }
      psum += __shfl_xor(psum, 1, 64);
      psum += __shfl_xor(psum, 2, 64);
      if (sub == 0) {
        sL[r] = sL[r] * fac + psum;
        sM[r] = mnew;
        sF[r] = fac;
      }
    }
    __syncthreads();

    // O rescale + P.V  (wave w owns v cols [w*48, w*48+48))
    {
      #pragma unroll
      for (int mi = 0; mi < 4; mi++) {
        #pragma unroll
        for (int r = 0; r < 4; r++) {
          float f = sF[mi * 16 + lr + r];
          #pragma unroll
          for (int ni = 0; ni < 3; ni++)
            oacc[mi][ni][r] *= f;
        }
      }
      #pragma unroll
      for (int kk = 0; kk < 2; kk++) {
        bf16x8 bvv[3];
        #pragma unroll
        for (int ni = 0; ni < 3; ni++)
          bvv[ni] = *(const bf16x8*)&sV[w * 48 + ni * 16 + lc][kk * 32 + (l >> 4) * 8];
        #pragma unroll
        for (int mi = 0; mi < 4; mi++) {
          bf16x8 ap = *(const bf16x8*)&sP[mi * 16 + lc][kk * 32 + (l >> 4) * 8];
          #pragma unroll
          for (int ni = 0; ni < 3; ni++)
            oacc[mi][ni] = __builtin_amdgcn_mfma_f32_16x16x32_bf16(ap, bvv[ni], oacc[mi][ni], 0, 0, 0);
        }
      }
    }
    __syncthreads();
  }

  #pragma unroll
  for (int mi = 0; mi < 4; mi++) {
    #pragma unroll
    for (int r = 0; r < 4; r++) {
      int q = mi * 16 + lr + r;
      float inv = 1.0f / sL[q];
      #pragma unroll
      for (int ni = 0; ni < 3; ni++) {
        AO[(size_t)(b * LL + q0 + q) * NVD + h * VDIM + w * 48 + ni * 16 + lc] =
            f2bf(oacc[mi][ni][r] * inv);
      }
    }
  }
}

}  // namespace

extern "C" void kernel_launch(void* const* d_in, const int* in_sizes, int n_in,
                              void* d_out, int out_size, void* d_ws, size_t ws_size,
                              hipStream_t stream) {
  (void)in_sizes; (void)n_in; (void)out_size; (void)ws_size;
  const float* x  = (const float*)d_in[0];
  const float* Wq = (const float*)d_in[1];
  const float* bq = (const float*)d_in[2];
  const float* Wk = (const float*)d_in[3];
  const float* bk = (const float*)d_in[4];
  const float* Wv = (const float*)d_in[5];
  const float* bv = (const float*)d_in[6];
  const float* Wo = (const float*)d_in[7];
  const float* bo = (const float*)d_in[8];
  const float* WR = (const float*)d_in[9];
  const float* uu = (const float*)d_in[10];
  // d_in[11] (v) intentionally unused: term4 is constant along the softmax axis.

  char* ws = (char*)d_ws;
  size_t off = 0;
  auto alloc = [&](size_t bytes) -> void* {
    void* p = ws + off;
    off += (bytes + 255) & ~(size_t)255;
    return p;
  };
  short* RB      = (short*)alloc((size_t)2048 * 64 * 2);
  unsigned* PMAX = (unsigned*)alloc(256);
  short* XB      = (short*)alloc((size_t)MR * CC * 2);
  short* WQT     = (short*)alloc((size_t)NQK * CC * 2);
  short* WKT     = (short*)alloc((size_t)NQK * CC * 2);
  short* WVT     = (short*)alloc((size_t)NVD * CC * 2);
  short* WOT     = (short*)alloc((size_t)CC * NVD * 2);
  short* QP      = (short*)alloc((size_t)MR * NQK * 2);
  short* QS      = (short*)alloc((size_t)MR * NQK * 2);
  short* KB      = (short*)alloc((size_t)MR * NQK * 2);
  short* VB      = (short*)alloc((size_t)MR * NVD * 2);
  short* VT      = (short*)alloc((size_t)MR * NVD * 2);
  short* AO      = (short*)alloc((size_t)MR * NVD * 2);

  hipMemsetAsync(PMAX, 0, 4, stream);
  k_f32_to_bf16<<<2048, 256, 0, stream>>>(x, XB, MR * CC);
  k_transpose_w<<<dim3(NQK / 32, CC / 32), dim3(32, 8), 0, stream>>>(Wq, WQT, CC, NQK);
  k_transpose_w<<<dim3(NQK / 32, CC / 32), dim3(32, 8), 0, stream>>>(Wk, WKT, CC, NQK);
  k_transpose_w<<<dim3(NVD / 32, CC / 32), dim3(32, 8), 0, stream>>>(Wv, WVT, CC, NVD);
  k_transpose_w<<<dim3(CC / 32, NVD / 32), dim3(32, 8), 0, stream>>>(Wo, WOT, NVD, CC);
  k_pdfmax<<<64, 256, 0, stream>>>(PMAX);
  k_build_r<<<2048, 256, 0, stream>>>(WR, PMAX, RB);
  k_gemm<1><<<dim3(MR / 128, NQK / 128), 256, 0, stream>>>(XB, WQT, MR, NQK, CC, bq, uu, QS, QP);
  k_gemm<0><<<dim3(MR / 128, NQK / 128), 256, 0, stream>>>(XB, WKT, MR, NQK, CC, bk, nullptr, KB, nullptr);
  k_gemm<0><<<dim3(MR / 128, NVD / 128), 256, 0, stream>>>(XB, WVT, MR, NVD, CC, bv, nullptr, VB, nullptr);
  k_transpose_v<<<dim3(LL / 32, VDIM / 32, BB * HH), dim3(32, 8), 0, stream>>>(VB, VT);
  k_attn<<<dim3(LL / 64, BB * HH), 256, 0, stream>>>(QP, QS, KB, VT, RB, AO);
  k_gemm<2><<<dim3(MR / 128, CC / 128), 256, 0, stream>>>(AO, WOT, MR, CC, NVD, bo, nullptr, d_out, nullptr);
}

// Round 2
// 429.510 us; speedup vs baseline: 1.0149x; 1.0149x over previous
//
#include <hip/hip_runtime.h>
#include <cstdint>
#include <cstddef>

typedef float f32x4 __attribute__((ext_vector_type(4)));
typedef short bf16x8 __attribute__((ext_vector_type(8)));

#define DEVI __device__ __forceinline__

namespace {

constexpr int BB = 8, LL = 1024, CC = 1536;
constexpr int HH = 8, KDIM = 64, VDIM = 192;
constexpr int NFEAT = 192, FSZ = 32;
constexpr float SCL = 0.125f;
constexpr int MR = BB * LL;     // 8192
constexpr int NQK = HH * KDIM;  // 512
constexpr int NVD = HH * VDIM;  // 1536

DEVI short f2bf(float f) {
  unsigned u = __float_as_uint(f);
  u = (u + 0x7FFFu + ((u >> 16) & 1u)) >> 16;
  return (short)u;
}

DEVI void gload_lds16(const void* g, void* l) {
  __builtin_amdgcn_global_load_lds(
      (const __attribute__((address_space(1))) void*)g,
      (__attribute__((address_space(3))) void*)l, 16, 0, 0);
}

// ---------------- convert f32 -> bf16 ----------------
__global__ void k_f32_to_bf16(const float* __restrict__ src, short* __restrict__ dst, int n) {
  int i0 = (blockIdx.x * blockDim.x + threadIdx.x) * 4;
  int stride = gridDim.x * blockDim.x * 4;
  for (int i = i0; i < n; i += stride) {
    float4 v = *reinterpret_cast<const float4*>(src + i);
    short4 o = { f2bf(v.x), f2bf(v.y), f2bf(v.z), f2bf(v.w) };
    *reinterpret_cast<short4*>(dst + i) = o;
  }
}

// ---------------- transpose f32 [R][Cd] -> bf16 [Cd][R] ----------------
__global__ void k_transpose_w(const float* __restrict__ src, short* __restrict__ dst, int R, int Cd) {
  __shared__ float tile[32][33];
  int c0 = blockIdx.x * 32, r0 = blockIdx.y * 32;
  int tx = threadIdx.x, ty = threadIdx.y;   // (32, 8)
  #pragma unroll
  for (int i = 0; i < 4; i++)
    tile[ty + i * 8][tx] = src[(size_t)(r0 + ty + i * 8) * Cd + c0 + tx];
  __syncthreads();
  #pragma unroll
  for (int i = 0; i < 4; i++)
    dst[(size_t)(c0 + ty + i * 8) * R + r0 + tx] = f2bf(tile[tx][ty + i * 8]);
}

// ---------------- V: [8192][1536] bf16 -> Vt [64][192][1024] bf16 ----------------
__global__ void k_transpose_v(const short* __restrict__ vb, short* __restrict__ vt) {
  __shared__ short tile[32][33];
  int bh = blockIdx.z;
  int b = bh >> 3, h = bh & 7;
  int v0 = blockIdx.y * 32;
  int s0 = blockIdx.x * 32;
  int tx = threadIdx.x, ty = threadIdx.y;
  #pragma unroll
  for (int i = 0; i < 4; i++)
    tile[ty + i * 8][tx] = vb[(size_t)(b * LL + s0 + ty + i * 8) * NVD + h * VDIM + v0 + tx];
  __syncthreads();
  #pragma unroll
  for (int i = 0; i < 4; i++)
    vt[(size_t)bh * VDIM * LL + (size_t)(v0 + ty + i * 8) * LL + s0 + tx] = tile[tx][ty + i * 8];
}

// ---------------- gamma pdf global max ----------------
__global__ void k_pdfmax(unsigned* slot) {
  int tid = blockIdx.x * blockDim.x + threadIdx.x;
  int nth = gridDim.x * blockDim.x;
  double lmax = 0.0;
  for (int idx = tid; idx < 2047 * FSZ; idx += nth) {
    int j = idx >> 5, i = idx & 31;
    double ap = (double)(j >= 1023 ? j - 1023 : 1023 - j);
    double mean = 32.0 + 32.0 * (double)i;
    double conc = (mean * (1.0 / 16.0)) * (mean * (1.0 / 16.0));
    double rate = mean * (1.0 / 256.0);
    double lp = (conc - 1.0) * log(ap) - rate * ap - lgamma(conc) + conc * log(rate);
    double pdf = exp(lp) + 1e-8;
    lmax = fmax(lmax, pdf);
  }
  float fv = (float)lmax;
  #pragma unroll
  for (int o = 32; o > 0; o >>= 1) fv = fmaxf(fv, __shfl_down(fv, o, 64));
  if ((threadIdx.x & 63) == 0) atomicMax(slot, __float_as_uint(fv));
}

// ---------------- build RB: row 0 = zeros, row j+1 = (basis[j] @ WR) ----------------
__global__ void k_build_r(const float* __restrict__ WR, const unsigned* __restrict__ slot,
                          short* __restrict__ rbuf) {
  __shared__ float feats[NFEAT];
  int jp = blockIdx.x;       // 0..2047
  int tid = threadIdx.x;     // 256
  if (jp == 0) {
    if (tid < KDIM) rbuf[tid] = 0;
    return;
  }
  int j = jp - 1;            // 0..2046
  int pos = j - (LL - 1);
  int api = pos < 0 ? -pos : pos;
  double ap = (double)api;
  float sgn = pos > 0 ? 1.0f : (pos < 0 ? -1.0f : 0.0f);
  if (tid < FSZ) {
    double xhl = 3.0 + 7.0 * (double)tid / 31.0;
    double hl = exp2(xhl);
    float fe = (float)exp2(-ap / hl);
    feats[tid] = fe; feats[FSZ + tid] = sgn * fe;
  } else if (tid < 2 * FSZ) {
    int i = tid - FSZ;
    double cw = exp2((double)(i + 1)) - 1.0;
    float fc = cw > ap ? 1.0f : 0.0f;
    feats[2 * FSZ + i] = fc; feats[3 * FSZ + i] = sgn * fc;
  } else if (tid < 3 * FSZ) {
    int i = tid - 2 * FSZ;
    double mean = 32.0 + 32.0 * (double)i;
    double conc = (mean * (1.0 / 16.0)) * (mean * (1.0 / 16.0));
    double rate = mean * (1.0 / 256.0);
    double lp = (conc - 1.0) * log(ap) - rate * ap - lgamma(conc) + conc * log(rate);
    double pdf = exp(lp) + 1e-8;
    float fg = (float)(pdf / (double)__uint_as_float(*slot));
    feats[4 * FSZ + i] = fg; feats[5 * FSZ + i] = sgn * fg;
  }
  __syncthreads();
  if (tid < KDIM) {
    float acc = 0.f;
    #pragma unroll 4
    for (int f = 0; f < NFEAT; f++) acc += feats[f] * WR[f * KDIM + tid];
    rbuf[jp * KDIM + tid] = f2bf(acc);
  }
}

// ---------------- bf16 MFMA GEMM: C = A[M,K] @ Bt[N,K]^T + bias ----------------
// MODE 0: bf16 store to D0.  MODE 1: D0=(val)*SCL bf16, D1=(val+bias2)*SCL bf16.  MODE 2: f32 store.
template<int MODE>
__global__ __launch_bounds__(256, 2)
void k_gemm(const short* __restrict__ A, const short* __restrict__ Bt,
            int Mdim, int Ndim, int Kdim,
            const float* __restrict__ bias, const float* __restrict__ bias2,
            void* __restrict__ D0, void* __restrict__ D1) {
  __shared__ short As[128][64];
  __shared__ short Bs[128][64];
  int m0 = blockIdx.x * 128, n0 = blockIdx.y * 128;
  int tid = threadIdx.x;
  int w = tid >> 6, l = tid & 63;
  int wr = (w >> 1) * 64, wc = (w & 1) * 64;

  f32x4 acc[4][4] = {};

  const short* ga = A + (size_t)(m0 + w * 8 + (l >> 3)) * Kdim + (l & 7) * 8;
  const short* gb = Bt + (size_t)(n0 + w * 8 + (l >> 3)) * Kdim + (l & 7) * 8;

  for (int k0 = 0; k0 < Kdim; k0 += 64) {
    #pragma unroll
    for (int i = 0; i < 4; i++) {
      gload_lds16(ga + (size_t)(i * 32) * Kdim + k0, &As[i * 32 + w * 8][0]);
      gload_lds16(gb + (size_t)(i * 32) * Kdim + k0, &Bs[i * 32 + w * 8][0]);
    }
    __syncthreads();
    #pragma unroll
    for (int kk = 0; kk < 2; kk++) {
      bf16x8 af[4], bfr[4];
      #pragma unroll
      for (int mi = 0; mi < 4; mi++)
        af[mi] = *(const bf16x8*)&As[wr + mi * 16 + (l & 15)][kk * 32 + (l >> 4) * 8];
      #pragma unroll
      for (int ni = 0; ni < 4; ni++)
        bfr[ni] = *(const bf16x8*)&Bs[wc + ni * 16 + (l & 15)][kk * 32 + (l >> 4) * 8];
      #pragma unroll
      for (int mi = 0; mi < 4; mi++)
        #pragma unroll
        for (int ni = 0; ni < 4; ni++)
          acc[mi][ni] = __builtin_amdgcn_mfma_f32_16x16x32_bf16(af[mi], bfr[ni], acc[mi][ni], 0, 0, 0);
    }
    __syncthreads();
  }

  int lr = (l >> 4) * 4, lc = l & 15;
  #pragma unroll
  for (int ni = 0; ni < 4; ni++) {
    int col = n0 + wc + ni * 16 + lc;
    float bvv = bias[col];
    float bv2 = (MODE == 1) ? bias2[col] : 0.f;
    #pragma unroll
    for (int mi = 0; mi < 4; mi++) {
      #pragma unroll
      for (int r = 0; r < 4; r++) {
        int row = m0 + wr + mi * 16 + lr + r;
        float val = acc[mi][ni][r] + bvv;
        if (MODE == 0) {
          ((short*)D0)[(size_t)row * Ndim + col] = f2bf(val);
        } else if (MODE == 1) {
          ((short*)D0)[(size_t)row * Ndim + col] = f2bf(val * SCL);
          ((short*)D1)[(size_t)row * Ndim + col] = f2bf((val + bv2) * SCL);
        } else {
          ((float*)D0)[(size_t)row * Ndim + col] = val;
        }
      }
    }
  }
}

// ---------------- flash attention with interleaved rel-shift term ----------------
// Qp = (Q+u)*SCL, Qs = Q*SCL (bf16, [8192][512]); Kb bf16 [8192][512];
// Vt bf16 [64][192][1024]; Rb bf16 [2048][64] (row 0 zeros); AO bf16 [8192][1536].
// Padded LDS (72 shorts / 68 floats per row) -> conflict-free b128 frag reads.
// S1 kept in registers by owning wave; S2 (parity-split) via sS2; in-register
// online softmax with per-lane running m/l; 4 barriers per k-tile.
__global__ __launch_bounds__(256, 2)
void k_attn(const short* __restrict__ Qp, const short* __restrict__ Qs,
            const short* __restrict__ Kb, const short* __restrict__ Vt,
            const short* __restrict__ Rb, short* __restrict__ AO) {
  __shared__ short sK[64][72];
  __shared__ short sV[192][72];
  __shared__ float sS2[64][68];
  __shared__ short sP[64][72];
  __shared__ float sF[64];
  __shared__ float sL[64];

  // XCD swizzle: blocks on XCD c cover bh in [c*8, c*8+8) across all 16 q-tiles.
  int bid = blockIdx.x;
  int swz = (bid & 7) * 128 + (bid >> 3);
  int qt = swz & 15, bh = swz >> 4;
  int b = bh >> 3, h = bh & 7;
  int q0 = qt * 64, qs0 = q0 >> 1;
  int tid = threadIdx.x;
  int w = tid >> 6, l = tid & 63;
  int hi = l >> 4, lc = l & 15;

  // Q fragments in registers (lane-fixed rows), loaded once.
  const short* qp = Qp + (size_t)(b * LL + q0 + w * 16 + lc) * NQK + h * KDIM;
  bf16x8 aq1[2] = { *(const bf16x8*)&qp[hi * 8], *(const bf16x8*)&qp[32 + hi * 8] };
  bool evenw = (w < 2);
  int s2r = evenw ? (w * 16 + lc) : ((w - 2) * 16 + 1 + lc);
  const short* qsg = Qs + (size_t)(b * LL + qs0 + s2r) * NQK + h * KDIM;
  bf16x8 aq2[2] = { *(const bf16x8*)&qsg[hi * 8], *(const bf16x8*)&qsg[32 + hi * 8] };
  int s2base = evenw ? (w * 16) : (32 + (w - 2) * 16);

  const short* kg = Kb + (size_t)(b * LL) * NQK + h * KDIM;
  const short* vg = Vt + (size_t)bh * VDIM * LL;

  float mrun[4] = { -INFINITY, -INFINITY, -INFINITY, -INFINITY };
  float lrun[4] = { 0.f, 0.f, 0.f, 0.f };
  f32x4 oacc[4][3] = {};

  for (int k0 = 0; k0 < LL; k0 += 64) {
    // stage K [64][64] and V^T [192][64] tiles (padded rows)
    for (int idx = tid; idx < 64 * 8; idx += 256) {
      int r = idx >> 3, c = (idx & 7) * 8;
      *(uint4*)&sK[r][c] = *(const uint4*)&kg[(size_t)(k0 + r) * NQK + c];
    }
    for (int idx = tid; idx < 192 * 8; idx += 256) {
      int r = idx >> 3, c = (idx & 7) * 8;
      *(uint4*)&sV[r][c] = *(const uint4*)&vg[(size_t)r * LL + k0 + c];
    }
    __syncthreads();

    // S1 into registers (own 16 q-rows) + S2 (parity-split) into sS2
    f32x4 s[4] = {};
    #pragma unroll
    for (int kk = 0; kk < 2; kk++) {
      #pragma unroll
      for (int ni = 0; ni < 4; ni++) {
        bf16x8 bk = *(const bf16x8*)&sK[ni * 16 + lc][kk * 32 + hi * 8];
        s[ni] = __builtin_amdgcn_mfma_f32_16x16x32_bf16(aq1[kk], bk, s[ni], 0, 0, 0);
      }
    }
    {
      const short* rb = Rb + (size_t)((evenw ? k0 + 1024 : k0) + lc) * KDIM;
      f32x4 s2[4] = {};
      #pragma unroll
      for (int kk = 0; kk < 2; kk++) {
        #pragma unroll
        for (int ni = 0; ni < 4; ni++) {
          bf16x8 br = *(const bf16x8*)&rb[(size_t)(ni * 16) * KDIM + kk * 32 + hi * 8];
          s2[ni] = __builtin_amdgcn_mfma_f32_16x16x32_bf16(aq2[kk], br, s2[ni], 0, 0, 0);
        }
      }
      #pragma unroll
      for (int ni = 0; ni < 4; ni++)
        #pragma unroll
        for (int r = 0; r < 4; r++)
          sS2[s2base + 4 * hi + r][ni * 16 + lc] = s2[ni][r];
    }
    __syncthreads();

    // add S2 into own rows; in-register online softmax (16-lane shfl reduce)
    #pragma unroll
    for (int r = 0; r < 4; r++) {
      int q = w * 16 + 4 * hi + r;
      int srow = (q >> 1) + ((q & 1) << 5);
      #pragma unroll
      for (int ni = 0; ni < 4; ni++)
        s[ni][r] += sS2[srow][ni * 16 + lc];
      float mx = fmaxf(fmaxf(s[0][r], s[1][r]), fmaxf(s[2][r], s[3][r]));
      mx = fmaxf(mx, __shfl_xor(mx, 1, 64));
      mx = fmaxf(mx, __shfl_xor(mx, 2, 64));
      mx = fmaxf(mx, __shfl_xor(mx, 4, 64));
      mx = fmaxf(mx, __shfl_xor(mx, 8, 64));
      float mnew = fmaxf(mrun[r], mx);
      float fac = __expf(mrun[r] - mnew);
      mrun[r] = mnew;
      float ps = 0.f;
      #pragma unroll
      for (int ni = 0; ni < 4; ni++) {
        float p = __expf(s[ni][r] - mnew);
        ps += p;
        sP[q][ni * 16 + lc] = f2bf(p);
      }
      ps += __shfl_xor(ps, 1, 64);
      ps += __shfl_xor(ps, 2, 64);
      ps += __shfl_xor(ps, 4, 64);
      ps += __shfl_xor(ps, 8, 64);
      lrun[r] = lrun[r] * fac + ps;
      if (lc == 0) sF[q] = fac;
    }
    __syncthreads();

    // O rescale + P.V (wave w owns v cols [w*48, w*48+48))
    #pragma unroll
    for (int mi = 0; mi < 4; mi++) {
      #pragma unroll
      for (int r = 0; r < 4; r++) {
        float f = sF[mi * 16 + 4 * hi + r];
        #pragma unroll
        for (int ni = 0; ni < 3; ni++)
          oacc[mi][ni][r] *= f;
      }
    }
    #pragma unroll
    for (int kk = 0; kk < 2; kk++) {
      bf16x8 bvv[3];
      #pragma unroll
      for (int ni = 0; ni < 3; ni++)
        bvv[ni] = *(const bf16x8*)&sV[w * 48 + ni * 16 + lc][kk * 32 + hi * 8];
      #pragma unroll
      for (int mi = 0; mi < 4; mi++) {
        bf16x8 ap = *(const bf16x8*)&sP[mi * 16 + lc][kk * 32 + hi * 8];
        #pragma unroll
        for (int ni = 0; ni < 3; ni++)
          oacc[mi][ni] = __builtin_amdgcn_mfma_f32_16x16x32_bf16(ap, bvv[ni], oacc[mi][ni], 0, 0, 0);
      }
    }
    __syncthreads();
  }

  if (lc == 0) {
    #pragma unroll
    for (int r = 0; r < 4; r++) sL[w * 16 + 4 * hi + r] = lrun[r];
  }
  __syncthreads();

  #pragma unroll
  for (int mi = 0; mi < 4; mi++) {
    #pragma unroll
    for (int r = 0; r < 4; r++) {
      int q = mi * 16 + 4 * hi + r;
      float inv = 1.0f / sL[q];
      #pragma unroll
      for (int ni = 0; ni < 3; ni++) {
        AO[(size_t)(b * LL + q0 + q) * NVD + h * VDIM + w * 48 + ni * 16 + lc] =
            f2bf(oacc[mi][ni][r] * inv);
      }
    }
  }
}

}  // namespace

extern "C" void kernel_launch(void* const* d_in, const int* in_sizes, int n_in,
                              void* d_out, int out_size, void* d_ws, size_t ws_size,
                              hipStream_t stream) {
  (void)in_sizes; (void)n_in; (void)out_size; (void)ws_size;
  const float* x  = (const float*)d_in[0];
  const float* Wq = (const float*)d_in[1];
  const float* bq = (const float*)d_in[2];
  const float* Wk = (const float*)d_in[3];
  const float* bk = (const float*)d_in[4];
  const float* Wv = (const float*)d_in[5];
  const float* bv = (const float*)d_in[6];
  const float* Wo = (const float*)d_in[7];
  const float* bo = (const float*)d_in[8];
  const float* WR = (const float*)d_in[9];
  const float* uu = (const float*)d_in[10];
  // d_in[11] (v) intentionally unused: term4 is constant along the softmax axis.

  char* ws = (char*)d_ws;
  size_t off = 0;
  auto alloc = [&](size_t bytes) -> void* {
    void* p = ws + off;
    off += (bytes + 255) & ~(size_t)255;
    return p;
  };
  short* RB      = (short*)alloc((size_t)2048 * 64 * 2);
  unsigned* PMAX = (unsigned*)alloc(256);
  short* XB      = (short*)alloc((size_t)MR * CC * 2);
  short* WQT     = (short*)alloc((size_t)NQK * CC * 2);
  short* WKT     = (short*)alloc((size_t)NQK * CC * 2);
  short* WVT     = (short*)alloc((size_t)NVD * CC * 2);
  short* WOT     = (short*)alloc((size_t)CC * NVD * 2);
  short* QP      = (short*)alloc((size_t)MR * NQK * 2);
  short* QS      = (short*)alloc((size_t)MR * NQK * 2);
  short* KB      = (short*)alloc((size_t)MR * NQK * 2);
  short* VB      = (short*)alloc((size_t)MR * NVD * 2);
  short* VT      = (short*)alloc((size_t)MR * NVD * 2);
  short* AO      = (short*)alloc((size_t)MR * NVD * 2);

  hipMemsetAsync(PMAX, 0, 4, stream);
  k_f32_to_bf16<<<2048, 256, 0, stream>>>(x, XB, MR * CC);
  k_transpose_w<<<dim3(NQK / 32, CC / 32), dim3(32, 8), 0, stream>>>(Wq, WQT, CC, NQK);
  k_transpose_w<<<dim3(NQK / 32, CC / 32), dim3(32, 8), 0, stream>>>(Wk, WKT, CC, NQK);
  k_transpose_w<<<dim3(NVD / 32, CC / 32), dim3(32, 8), 0, stream>>>(Wv, WVT, CC, NVD);
  k_transpose_w<<<dim3(CC / 32, NVD / 32), dim3(32, 8), 0, stream>>>(Wo, WOT, NVD, CC);
  k_pdfmax<<<64, 256, 0, stream>>>(PMAX);
  k_build_r<<<2048, 256, 0, stream>>>(WR, PMAX, RB);
  k_gemm<1><<<dim3(MR / 128, NQK / 128), 256, 0, stream>>>(XB, WQT, MR, NQK, CC, bq, uu, QS, QP);
  k_gemm<0><<<dim3(MR / 128, NQK / 128), 256, 0, stream>>>(XB, WKT, MR, NQK, CC, bk, nullptr, KB, nullptr);
  k_gemm<0><<<dim3(MR / 128, NVD / 128), 256, 0, stream>>>(XB, WVT, MR, NVD, CC, bv, nullptr, VB, nullptr);
  k_transpose_v<<<dim3(LL / 32, VDIM / 32, BB * HH), dim3(32, 8), 0, stream>>>(VB, VT);
  k_attn<<<dim3(LL / 64 * BB * HH), 256, 0, stream>>>(QP, QS, KB, VT, RB, AO);
  k_gemm<2><<<dim3(MR / 128, CC / 128), 256, 0, stream>>>(AO, WOT, MR, CC, NVD, bo, nullptr, d_out, nullptr);
}